// Round 8
// baseline (4618.587 us; speedup 1.0000x reference)
//
#include <hip/hip_runtime.h>
#include <math.h>

// ---------------------------------------------------------------------------
// Persistent 2-layer LSTM via MFMA split-bf16 (hi+lo, 3-term) fp32 emulation.
// 208 blocks x 512 thr (1/CU). Pipeline: A(64)=layer0 s=t | B(128)=layer1
// s=t-1 | C(16)=proj s=t-2.
// R13: persistent-register weights (zero in-loop weight loads; FETCH -25x).
// R14: (a) all-quarters-upfront h staging -- A/C issue 4 quarters at step
// start (waits 12/8/4/0); B holds 4 reg slots, issues q0-3 upfront and q4-7
// after each phase barrier (slot reuse safe: lgkmcnt(0) drains ds_writes
// before reissue), waits {12,12,12,12,12,8,4,0}. (b) distributed single-hop
// flag barrier: every block polls all 208 flags (wave 0), no root/gen hop.
// ---------------------------------------------------------------------------

typedef __attribute__((ext_vector_type(8))) short short8;
typedef __attribute__((ext_vector_type(4))) float f32x4;

constexpr int kV = 256, kH = 1024, kB = 32, kS = 512, G4H = 4096;
constexpr int NT = 512, NBLK = 208;
constexpr int NA = 64, B0 = 64, C0 = 192;

// ws layout in SHORT units
constexpr long SZW = 4194304L;            // shorts per packed 1024x4096 matrix
constexpr long SZY = 262144L;             // shorts per packed Why array
constexpr long WP0H = 0,        WP0L = SZW;
constexpr long WP1XH = 2*SZW,   WP1XL = 3*SZW;
constexpr long WP1HH = 4*SZW,   WP1HL = 5*SZW;
constexpr long WYH  = 6*SZW,    WYL  = 6*SZW + SZY;
constexpr long HOFF = 6*SZW + 2*SZY;      // h arrays: h0h[2][32K],h0l,h1h,h1l

#define MFMA(a,b,c) __builtin_amdgcn_mfma_f32_16x16x32_bf16(a, b, c, 0, 0, 0)

#define VM_WAIT(n) do { \
    asm volatile("s_waitcnt vmcnt(" #n ")" ::: "memory"); \
    __builtin_amdgcn_sched_barrier(0); \
  } while (0)

// asm weight load (prevents compiler rematerialization from memory)
#define WLOAD(dst, p) \
  asm volatile("global_load_dwordx4 %0, %1, off" : "=v"(dst) : "v"(p) : "memory")

__device__ __forceinline__ float sigmoidf_(float v) { return 1.f / (1.f + expf(-v)); }

__device__ __forceinline__ void bf16split(float w, unsigned& hi, unsigned& lo) {
  unsigned u = __float_as_uint(w);
  unsigned r = (u + 0x7fffu + ((u >> 16) & 1u)) >> 16;
  float res = w - __uint_as_float(r << 16);
  unsigned u2 = __float_as_uint(res);
  unsigned r2 = (u2 + 0x7fffu + ((u2 >> 16) & 1u)) >> 16;
  hi = r; lo = r2;
}

// ---------------- coherent (cache-bypass) helpers --------------------------

__device__ __forceinline__ void coh_store_u32(unsigned* p, unsigned v) {
  asm volatile("global_store_dword %0, %1, off sc0 sc1" :: "v"(p), "v"(v) : "memory");
}
__device__ __forceinline__ void coh_store_u16(unsigned short* p, unsigned v) {
  asm volatile("global_store_short %0, %1, off sc0 sc1" :: "v"(p), "v"(v) : "memory");
}

// issue one 256-k quarter of h (hi+lo): 4 coherent 16B loads, NO wait.
__device__ __forceinline__ void stage_issue4(const unsigned short* pr0h,
                                             const unsigned short* pr1h,
                                             const unsigned short* pr0l,
                                             const unsigned short* pr1l,
                                             int qoff,   // qtr*256 (shorts)
                                             float4& a, float4& b,
                                             float4& c, float4& d) {
  asm volatile(
      "global_load_dwordx4 %0, %4, off sc0 sc1\n\t"
      "global_load_dwordx4 %1, %5, off sc0 sc1\n\t"
      "global_load_dwordx4 %2, %6, off sc0 sc1\n\t"
      "global_load_dwordx4 %3, %7, off sc0 sc1"
      : "=&v"(a), "=&v"(b), "=&v"(c), "=&v"(d)
      : "v"(pr0h + qoff), "v"(pr1h + qoff), "v"(pr0l + qoff), "v"(pr1l + qoff)
      : "memory");
}

__device__ __forceinline__ void stage_write4(short8* HH, short8* HL,
                                             int b0_, int kg,
                                             const float4& a, const float4& b,
                                             const float4& c, const float4& d) {
  HH[b0_ * 33 + kg]        = __builtin_bit_cast(short8, a);
  HH[(b0_ + 16) * 33 + kg] = __builtin_bit_cast(short8, b);
  HL[b0_ * 33 + kg]        = __builtin_bit_cast(short8, c);
  HL[(b0_ + 16) * 33 + kg] = __builtin_bit_cast(short8, d);
}

// barrier that does NOT drain vmcnt: LDS-drain + raw s_barrier.
__device__ __forceinline__ void lds_barrier() {
  asm volatile("s_waitcnt lgkmcnt(0)" ::: "memory");
  __builtin_amdgcn_sched_barrier(0);
  __builtin_amdgcn_s_barrier();
  __builtin_amdgcn_sched_barrier(0);
}

// ---------------- distributed single-hop flag barrier ----------------------

__device__ __forceinline__ void flag_barrier(unsigned* arrive,
                                             int blk, int tid, int t) {
  __syncthreads();                         // drains vmcnt per wave
  const unsigned target = (unsigned)(t + 1);
  if (tid == 0) coh_store_u32(arrive + blk * 16, target);
  if (tid < 64) {
    const unsigned* q0 = arrive + tid * 16;
    const unsigned* q1 = arrive + (64 + tid) * 16;
    const unsigned* q2 = arrive + (128 + tid) * 16;
    const int i3 = (192 + tid < NBLK) ? (192 + tid) : 0;
    const unsigned* q3 = arrive + i3 * 16;
    int guard = 0;
    for (;;) {
      unsigned a, b, c, d;
      asm volatile(
          "global_load_dword %0, %4, off sc0 sc1\n\t"
          "global_load_dword %1, %5, off sc0 sc1\n\t"
          "global_load_dword %2, %6, off sc0 sc1\n\t"
          "global_load_dword %3, %7, off sc0 sc1\n\t"
          "s_waitcnt vmcnt(0)"
          : "=&v"(a), "=&v"(b), "=&v"(c), "=&v"(d)
          : "v"(q0), "v"(q1), "v"(q2), "v"(q3) : "memory");
      bool ok = (a >= target) && (b >= target) && (c >= target) && (d >= target);
      if (__all(ok)) break;
      __builtin_amdgcn_s_sleep(1);
      if (++guard > (1 << 17)) break;      // anti-hang valve
    }
  }
  __syncthreads();
}

// -------------------------- prep kernels -----------------------------------

__global__ void pack_w(const float* __restrict__ in, unsigned short* __restrict__ hi,
                       unsigned short* __restrict__ lo, int ncols) {
  int id = blockIdx.x * 256 + threadIdx.x;
  int slab = id / ncols, row = id % ncols;   // slab < 128
  int k0 = (slab >> 2) * 32 + (slab & 3) * 8;
  long ob = ((long)slab * ncols + row) * 8;
  #pragma unroll
  for (int e = 0; e < 8; ++e) {
    float w = in[(long)(k0 + e) * ncols + row];
    unsigned h_, l_;
    bf16split(w, h_, l_);
    hi[ob + e] = (unsigned short)h_;
    lo[ob + e] = (unsigned short)l_;
  }
}

__global__ void zero_state(unsigned* __restrict__ p, int n) {
  int i = blockIdx.x * 256 + threadIdx.x;
  if (i < n) p[i] = 0u;
}

// -------------------------- main persistent kernel -------------------------

extern "C" __global__ void __launch_bounds__(512, 1)
lstm_persist(const int* __restrict__ x,
             const float* __restrict__ Wx0,
             const float* __restrict__ b0v,
             const float* __restrict__ b1v,
             const float* __restrict__ byv,
             unsigned short* __restrict__ wss,
             float* __restrict__ out) {
  const short8* wp0h  = (const short8*)(wss + WP0H);
  const short8* wp0l  = (const short8*)(wss + WP0L);
  const short8* wp1xh = (const short8*)(wss + WP1XH);
  const short8* wp1xl = (const short8*)(wss + WP1XL);
  const short8* wp1hh = (const short8*)(wss + WP1HH);
  const short8* wp1hl = (const short8*)(wss + WP1HL);
  const short8* wyh   = (const short8*)(wss + WYH);
  const short8* wyl   = (const short8*)(wss + WYL);
  unsigned short* h0h = wss + HOFF;            // [2][32][1024]
  unsigned short* h0l = h0h + 65536;
  unsigned short* h1h = h0h + 131072;
  unsigned short* h1l = h0h + 196608;
  unsigned* arrive = (unsigned*)(h0h + 262144);  // stride-16 flags

  const int tid = threadIdx.x, blk = blockIdx.x;
  const int lane = tid & 63, m = lane & 15, quad = lane >> 4, w = tid >> 6;
  const int b0_ = tid >> 5, kg = tid & 31;     // staging row / chunk
  const int kg8 = kg * 8;

  __shared__ short8 HSH[2][32 * 33];   // 2 x 16.5 KB  h hi quarter (dbuf)
  __shared__ short8 HSL[2][32 * 33];   // 2 x 16.5 KB  h lo quarter (dbuf)
  __shared__ float gx[4096];           // 16 KB partial-sum exchange

  if (blk < NA) {
    // ================= A: layer0 cell, s = t ===========================
    const int g = w >> 1, kh = w & 1, j0A = blk * 16;
    const int ue = tid >> 5, be = tid & 31, j2e = j0A + ue;
    const float bA0 = b0v[j2e],          bA1 = b0v[kH + j2e];
    const float bA2 = b0v[2 * kH + j2e], bA3 = b0v[3 * kH + j2e];
    // persistent weight slice: 16 kk (parity kh) x hi/lo = 128 VGPR
    const short8* ah_ = wp0h + quad * 4096 + (g * 1024 + j0A + m);
    const short8* al_ = wp0l + quad * 4096 + (g * 1024 + j0A + m);
    short8 wah[16], wal[16];
    #pragma unroll
    for (int i = 0; i < 16; ++i) {
      WLOAD(wah[i], &ah_[(2 * i + kh) * 16384]);
      WLOAD(wal[i], &al_[(2 * i + kh) * 16384]);
    }
    VM_WAIT(0);
    float c0r = 0.f;

    #pragma unroll 1
    for (int t = 0; t < kS + 2; ++t) {
      const int s = t;
      if (s < kS) {
        const int rpar = (s + 1) & 1;
        const unsigned short* gH = h0h + rpar * 32768;
        const unsigned short* gL = h0l + rpar * 32768;
        const unsigned short* pH0 = gH + b0_ * 1024 + kg8;
        const unsigned short* pH1 = pH0 + 16 * 1024;
        const unsigned short* pL0 = gL + b0_ * 1024 + kg8;
        const unsigned short* pL1 = pL0 + 16 * 1024;
        // xs first (compiler load + its own drain), then asm gather, stages
        const int xs = x[be * kS + s];
        const float* wxp = Wx0 + (long)xs * G4H + j2e;
        float wxi, wxf, wxg, wxo;
        asm volatile(
            "global_load_dword %0, %4, off\n\t"
            "global_load_dword %1, %5, off\n\t"
            "global_load_dword %2, %6, off\n\t"
            "global_load_dword %3, %7, off"
            : "=&v"(wxi), "=&v"(wxf), "=&v"(wxg), "=&v"(wxo)
            : "v"(wxp), "v"(wxp + kH), "v"(wxp + 2 * kH), "v"(wxp + 3 * kH)
            : "memory");
        // all 4 quarters upfront: queue = [wx(4), q0..q3(16)]
        float4 st[4][4];
        stage_issue4(pH0, pH1, pL0, pL1, 0,   st[0][0], st[0][1], st[0][2], st[0][3]);
        stage_issue4(pH0, pH1, pL0, pL1, 256, st[1][0], st[1][1], st[1][2], st[1][3]);
        stage_issue4(pH0, pH1, pL0, pL1, 512, st[2][0], st[2][1], st[2][2], st[2][3]);
        stage_issue4(pH0, pH1, pL0, pL1, 768, st[3][0], st[3][1], st[3][2], st[3][3]);
        f32x4 acc0 = {0.f, 0.f, 0.f, 0.f}, acc1 = {0.f, 0.f, 0.f, 0.f};
        #pragma unroll
        for (int ph = 0; ph < 4; ++ph) {
          if (ph == 0)      { VM_WAIT(12); }   // retires wx + q0
          else if (ph == 1) { VM_WAIT(8);  }
          else if (ph == 2) { VM_WAIT(4);  }
          else              { VM_WAIT(0);  }
          stage_write4(&HSH[ph & 1][0], &HSL[ph & 1][0], b0_, kg,
                       st[ph][0], st[ph][1], st[ph][2], st[ph][3]);
          lds_barrier();
          #pragma unroll
          for (int i2 = 0; i2 < 4; ++i2) {
            const int kl = 2 * i2 + kh;          // runtime kh, fine
            const int widx = ph * 4 + i2;        // compile-time
            short8 bh0 = HSH[ph & 1][m * 33 + kl * 4 + quad];
            short8 bl0 = HSL[ph & 1][m * 33 + kl * 4 + quad];
            short8 bh1 = HSH[ph & 1][(16 + m) * 33 + kl * 4 + quad];
            short8 bl1 = HSL[ph & 1][(16 + m) * 33 + kl * 4 + quad];
            acc0 = MFMA(wah[widx], bh0, acc0);
            acc0 = MFMA(wah[widx], bl0, acc0);
            acc0 = MFMA(wal[widx], bh0, acc0);
            acc1 = MFMA(wah[widx], bh1, acc1);
            acc1 = MFMA(wah[widx], bl1, acc1);
            acc1 = MFMA(wal[widx], bh1, acc1);
          }
        }
        #pragma unroll
        for (int r = 0; r < 4; ++r) {
          gx[(kh * 64 + g * 16 + quad * 4 + r) * 32 + m]      = acc0[r];
          gx[(kh * 64 + g * 16 + quad * 4 + r) * 32 + 16 + m] = acc1[r];
        }
        lds_barrier();
        {
          float gi = gx[(0 + ue) * 32 + be]  + gx[(64 + 0 + ue) * 32 + be]  + wxi + bA0;
          float gf = gx[(16 + ue) * 32 + be] + gx[(64 + 16 + ue) * 32 + be] + wxf + bA1;
          float gg = gx[(32 + ue) * 32 + be] + gx[(64 + 32 + ue) * 32 + be] + wxg + bA2;
          float go = gx[(48 + ue) * 32 + be] + gx[(64 + 48 + ue) * 32 + be] + wxo + bA3;
          float cc = sigmoidf_(gf) * c0r + sigmoidf_(gi) * tanhf(gg);
          float hh = sigmoidf_(go) * tanhf(cc);
          c0r = cc;
          unsigned h_, l_;
          bf16split(hh, h_, l_);
          const int wpar = s & 1;
          coh_store_u16(h0h + wpar * 32768 + be * 1024 + j2e, h_);
          coh_store_u16(h0l + wpar * 32768 + be * 1024 + j2e, l_);
        }
      }
      if (t < kS + 1) flag_barrier(arrive, blk, tid, t);
    }
  } else if (blk < C0) {
    // ================= B: layer1 cell, s = t-1 =========================
    const int hf = w >> 2, mt = (w >> 1) & 1, kq = w & 1;
    const int rowB = mt * 16 + m;
    const int growB = (rowB >> 3) * 1024 + (blk - B0) * 8 + (rowB & 7);
    const int ub = tid >> 5;
    const int j2b = (blk - B0) * 8 + (ub & 7);
    const float bB0 = b1v[j2b],          bB1 = b1v[kH + j2b];
    const float bB2 = b1v[2 * kH + j2b], bB3 = b1v[3 * kH + j2b];
    // persistent slice: matrix hf, 16 kk (parity kq) x hi/lo = 128 VGPR
    const short8* bh_ = (hf ? wp1hh : wp1xh) + quad * 4096 + growB;
    const short8* bl_ = (hf ? wp1hl : wp1xl) + quad * 4096 + growB;
    short8 wbh[16], wbl[16];
    #pragma unroll
    for (int i = 0; i < 16; ++i) {
      WLOAD(wbh[i], &bh_[(2 * i + kq) * 16384]);
      WLOAD(wbl[i], &bl_[(2 * i + kq) * 16384]);
    }
    VM_WAIT(0);
    float c1r = 0.f;

    #pragma unroll 1
    for (int t = 0; t < kS + 2; ++t) {
      const int s = t - 1;
      if (s >= 0 && s < kS) {
        const unsigned short* g0h = h0h + (s & 1) * 32768;
        const unsigned short* g0l = h0l + (s & 1) * 32768;
        const unsigned short* g1h = h1h + ((s + 1) & 1) * 32768;
        const unsigned short* g1l = h1l + ((s + 1) & 1) * 32768;
        const unsigned short* pA0h = g0h + b0_ * 1024 + kg8;
        const unsigned short* pA1h = pA0h + 16 * 1024;
        const unsigned short* pA0l = g0l + b0_ * 1024 + kg8;
        const unsigned short* pA1l = pA0l + 16 * 1024;
        const unsigned short* pB0h = g1h + b0_ * 1024 + kg8;
        const unsigned short* pB1h = pB0h + 16 * 1024;
        const unsigned short* pB0l = g1l + b0_ * 1024 + kg8;
        const unsigned short* pB1l = pB0l + 16 * 1024;
        // q0..q3 (h0) upfront; q4..q7 (h1) reissued per phase after barrier
        float4 st[4][4];
        stage_issue4(pA0h, pA1h, pA0l, pA1l, 0,   st[0][0], st[0][1], st[0][2], st[0][3]);
        stage_issue4(pA0h, pA1h, pA0l, pA1l, 256, st[1][0], st[1][1], st[1][2], st[1][3]);
        stage_issue4(pA0h, pA1h, pA0l, pA1l, 512, st[2][0], st[2][1], st[2][2], st[2][3]);
        stage_issue4(pA0h, pA1h, pA0l, pA1l, 768, st[3][0], st[3][1], st[3][2], st[3][3]);
        f32x4 acc0 = {0.f, 0.f, 0.f, 0.f}, acc1 = {0.f, 0.f, 0.f, 0.f};
        #pragma unroll
        for (int ph = 0; ph < 8; ++ph) {
          const int half = ph >> 2, qtr = ph & 3;
          if (ph < 5)       { VM_WAIT(12); }
          else if (ph == 5) { VM_WAIT(8);  }
          else if (ph == 6) { VM_WAIT(4);  }
          else              { VM_WAIT(0);  }
          stage_write4(&HSH[ph & 1][0], &HSL[ph & 1][0], b0_, kg,
                       st[ph & 3][0], st[ph & 3][1], st[ph & 3][2], st[ph & 3][3]);
          lds_barrier();           // lgkmcnt(0) first -> slot regs reusable
          if (ph < 4)              // issue q(ph+4) into the slot just drained
            stage_issue4(pB0h, pB1h, pB0l, pB1l, ph * 256,
                         st[ph & 3][0], st[ph & 3][1], st[ph & 3][2], st[ph & 3][3]);
          if (hf == half) {
            #pragma unroll
            for (int i2 = 0; i2 < 4; ++i2) {
              const int kl = 2 * i2 + kq;
              const int widx = qtr * 4 + i2;
              short8 bh0 = HSH[ph & 1][m * 33 + kl * 4 + quad];
              short8 bl0 = HSL[ph & 1][m * 33 + kl * 4 + quad];
              short8 bh1 = HSH[ph & 1][(16 + m) * 33 + kl * 4 + quad];
              short8 bl1 = HSL[ph & 1][(16 + m) * 33 + kl * 4 + quad];
              acc0 = MFMA(wbh[widx], bh0, acc0);
              acc0 = MFMA(wbh[widx], bl0, acc0);
              acc0 = MFMA(wbl[widx], bh0, acc0);
              acc1 = MFMA(wbh[widx], bh1, acc1);
              acc1 = MFMA(wbh[widx], bl1, acc1);
              acc1 = MFMA(wbl[widx], bh1, acc1);
            }
          }
        }
        #pragma unroll
        for (int r = 0; r < 4; ++r) {
          const int rg = hf * 2 + kq;
          gx[(rg * 32 + mt * 16 + quad * 4 + r) * 32 + m]      = acc0[r];
          gx[(rg * 32 + mt * 16 + quad * 4 + r) * 32 + 16 + m] = acc1[r];
        }
        lds_barrier();
        if (tid < 256) {
          const int u = tid >> 5, b = tid & 31;
          float gt[4];
          #pragma unroll
          for (int g2 = 0; g2 < 4; ++g2) {
            const int row = g2 * 8 + u;
            gt[g2] = gx[(row) * 32 + b] + gx[(32 + row) * 32 + b] +
                     gx[(64 + row) * 32 + b] + gx[(96 + row) * 32 + b];
          }
          float gt0 = gt[0] + bB0, gt1 = gt[1] + bB1;
          float gt2 = gt[2] + bB2, gt3 = gt[3] + bB3;
          float cc = sigmoidf_(gt1) * c1r + sigmoidf_(gt0) * tanhf(gt2);
          float hh = sigmoidf_(gt3) * tanhf(cc);
          c1r = cc;
          unsigned h_, l_;
          bf16split(hh, h_, l_);
          const int wpar = s & 1;
          const int j2 = (blk - B0) * 8 + u;
          coh_store_u16(h1h + wpar * 32768 + b * 1024 + j2, h_);
          coh_store_u16(h1l + wpar * 32768 + b * 1024 + j2, l_);
        }
      }
      if (t < kS + 1) flag_barrier(arrive, blk, tid, t);
    }
  } else {
    // ================= C: vocab projection, s = t-2 ====================
    const int growC = (blk - C0) * 16 + m;
    const float byr = byv[(blk - C0) * 16 + (tid & 15)];
    // persistent slice: 4 kk (kl == w) x hi/lo = 32 VGPR
    const short8* ch_ = wyh + quad * 256 + growC;
    const short8* cl_ = wyl + quad * 256 + growC;
    short8 wch[4], wcl[4];
    #pragma unroll
    for (int i = 0; i < 4; ++i) {
      WLOAD(wch[i], &ch_[(i * 8 + w) * 1024]);
      WLOAD(wcl[i], &cl_[(i * 8 + w) * 1024]);
    }
    VM_WAIT(0);

    #pragma unroll 1
    for (int t = 0; t < kS + 2; ++t) {
      const int s = t - 2;
      if (s >= 0 && s < kS) {
        const int rpar = s & 1;
        const unsigned short* gH = h1h + rpar * 32768;
        const unsigned short* gL = h1l + rpar * 32768;
        const unsigned short* pH0 = gH + b0_ * 1024 + kg8;
        const unsigned short* pH1 = pH0 + 16 * 1024;
        const unsigned short* pL0 = gL + b0_ * 1024 + kg8;
        const unsigned short* pL1 = pL0 + 16 * 1024;
        float4 st[4][4];
        stage_issue4(pH0, pH1, pL0, pL1, 0,   st[0][0], st[0][1], st[0][2], st[0][3]);
        stage_issue4(pH0, pH1, pL0, pL1, 256, st[1][0], st[1][1], st[1][2], st[1][3]);
        stage_issue4(pH0, pH1, pL0, pL1, 512, st[2][0], st[2][1], st[2][2], st[2][3]);
        stage_issue4(pH0, pH1, pL0, pL1, 768, st[3][0], st[3][1], st[3][2], st[3][3]);
        f32x4 acc0 = {0.f, 0.f, 0.f, 0.f}, acc1 = {0.f, 0.f, 0.f, 0.f};
        #pragma unroll
        for (int ph = 0; ph < 4; ++ph) {
          if (ph == 0)      { VM_WAIT(12); }
          else if (ph == 1) { VM_WAIT(8);  }
          else if (ph == 2) { VM_WAIT(4);  }
          else              { VM_WAIT(0);  }
          stage_write4(&HSH[ph & 1][0], &HSL[ph & 1][0], b0_, kg,
                       st[ph][0], st[ph][1], st[ph][2], st[ph][3]);
          lds_barrier();
          {
            const int kl = w;                  // wave-uniform
            short8 bh0 = HSH[ph & 1][m * 33 + kl * 4 + quad];
            short8 bl0 = HSL[ph & 1][m * 33 + kl * 4 + quad];
            short8 bh1 = HSH[ph & 1][(16 + m) * 33 + kl * 4 + quad];
            short8 bl1 = HSL[ph & 1][(16 + m) * 33 + kl * 4 + quad];
            acc0 = MFMA(wch[ph], bh0, acc0);
            acc0 = MFMA(wch[ph], bl0, acc0);
            acc0 = MFMA(wcl[ph], bh0, acc0);
            acc1 = MFMA(wch[ph], bh1, acc1);
            acc1 = MFMA(wch[ph], bl1, acc1);
            acc1 = MFMA(wcl[ph], bh1, acc1);
          }
        }
        #pragma unroll
        for (int r = 0; r < 4; ++r) {
          gx[(w * 16 + quad * 4 + r) * 32 + m]      = acc0[r];
          gx[(w * 16 + quad * 4 + r) * 32 + 16 + m] = acc1[r];
        }
        lds_barrier();
        {
          const int b = tid >> 4, vl = tid & 15;
          const int vg = (blk - C0) * 16 + vl;
          float sum = byr;
          #pragma unroll
          for (int rg = 0; rg < 8; ++rg) sum += gx[(rg * 16 + vl) * 32 + b];
          out[(s * kB + b) * kV + vg] = sum;
        }
      }
      if (t < kS + 1) flag_barrier(arrive, blk, tid, t);
    }
  }
}

// -------------------------- host launcher ----------------------------------

extern "C" void kernel_launch(void* const* d_in, const int* in_sizes, int n_in,
                              void* d_out, int out_size, void* d_ws, size_t ws_size,
                              hipStream_t stream) {
  const int*   x   = (const int*)d_in[0];
  const float* Wx0 = (const float*)d_in[1];
  const float* Wh0 = (const float*)d_in[2];
  const float* b0v = (const float*)d_in[3];
  const float* Wx1 = (const float*)d_in[4];
  const float* Wh1 = (const float*)d_in[5];
  const float* b1v = (const float*)d_in[6];
  const float* Why = (const float*)d_in[7];
  const float* byv = (const float*)d_in[8];
  unsigned short* wss = (unsigned short*)d_ws;
  float* outp = (float*)d_out;

  hipLaunchKernelGGL(pack_w, dim3(2048), dim3(256), 0, stream,
                     Wh0, wss + WP0H, wss + WP0L, G4H);
  hipLaunchKernelGGL(pack_w, dim3(2048), dim3(256), 0, stream,
                     Wx1, wss + WP1XH, wss + WP1XL, G4H);
  hipLaunchKernelGGL(pack_w, dim3(2048), dim3(256), 0, stream,
                     Wh1, wss + WP1HH, wss + WP1HL, G4H);
  hipLaunchKernelGGL(pack_w, dim3(128), dim3(256), 0, stream,
                     Why, wss + WYH, wss + WYL, kV);
  // zero h arrays (262144 shorts = 131072 u32) + flags (4097 u32)
  hipLaunchKernelGGL(zero_state, dim3(529), dim3(256), 0, stream,
                     (unsigned*)(wss + HOFF), 131072 + 4100);

  hipLaunchKernelGGL(lstm_persist, dim3(NBLK), dim3(NT), 0, stream,
                     x, Wx0, b0v, b1v, byv, wss, outp);
}

// Round 9
// 4343.791 us; speedup vs baseline: 1.0633x; 1.0633x over previous
//
#include <hip/hip_runtime.h>
#include <math.h>

// ---------------------------------------------------------------------------
// Persistent 2-layer LSTM via MFMA split-bf16 (hi+lo, 3-term) fp32 emulation.
// 208 blocks x 512 thr (1/CU). Pipeline: A(64)=layer0 s=t | B(128)=layer1
// s=t-1 | C(16)=proj s=t-2.
// R13: persistent-register weights (zero in-loop weight loads; FETCH -25x).
// R14: all-quarters-upfront h staging (A/C waits 12/8/4/0; B slot-reuse,
// waits {12x5,8,4,0}).
// R15: A/B isolation -- R14 staging kept, R13 two-hop ROOT flag barrier
// restored (R14's all-blocks-poll-all-flags barrier caused ~200x coherent
// polling traffic on the flag lines; MfmaUtil/VALUBusy both fell).
// ---------------------------------------------------------------------------

typedef __attribute__((ext_vector_type(8))) short short8;
typedef __attribute__((ext_vector_type(4))) float f32x4;

constexpr int kV = 256, kH = 1024, kB = 32, kS = 512, G4H = 4096;
constexpr int NT = 512, NBLK = 208;
constexpr int NA = 64, B0 = 64, C0 = 192, ROOT = NBLK - 1;

// ws layout in SHORT units
constexpr long SZW = 4194304L;            // shorts per packed 1024x4096 matrix
constexpr long SZY = 262144L;             // shorts per packed Why array
constexpr long WP0H = 0,        WP0L = SZW;
constexpr long WP1XH = 2*SZW,   WP1XL = 3*SZW;
constexpr long WP1HH = 4*SZW,   WP1HL = 5*SZW;
constexpr long WYH  = 6*SZW,    WYL  = 6*SZW + SZY;
constexpr long HOFF = 6*SZW + 2*SZY;      // h arrays: h0h[2][32K],h0l,h1h,h1l

#define MFMA(a,b,c) __builtin_amdgcn_mfma_f32_16x16x32_bf16(a, b, c, 0, 0, 0)

#define VM_WAIT(n) do { \
    asm volatile("s_waitcnt vmcnt(" #n ")" ::: "memory"); \
    __builtin_amdgcn_sched_barrier(0); \
  } while (0)

// asm weight load (prevents compiler rematerialization from memory)
#define WLOAD(dst, p) \
  asm volatile("global_load_dwordx4 %0, %1, off" : "=v"(dst) : "v"(p) : "memory")

__device__ __forceinline__ float sigmoidf_(float v) { return 1.f / (1.f + expf(-v)); }

__device__ __forceinline__ void bf16split(float w, unsigned& hi, unsigned& lo) {
  unsigned u = __float_as_uint(w);
  unsigned r = (u + 0x7fffu + ((u >> 16) & 1u)) >> 16;
  float res = w - __uint_as_float(r << 16);
  unsigned u2 = __float_as_uint(res);
  unsigned r2 = (u2 + 0x7fffu + ((u2 >> 16) & 1u)) >> 16;
  hi = r; lo = r2;
}

// ---------------- coherent (cache-bypass) helpers --------------------------

__device__ __forceinline__ void coh_store_u32(unsigned* p, unsigned v) {
  asm volatile("global_store_dword %0, %1, off sc0 sc1" :: "v"(p), "v"(v) : "memory");
}
__device__ __forceinline__ void coh_store_u16(unsigned short* p, unsigned v) {
  asm volatile("global_store_short %0, %1, off sc0 sc1" :: "v"(p), "v"(v) : "memory");
}
__device__ __forceinline__ unsigned coh_load_u32(const unsigned* p) {
  unsigned v;
  asm volatile("global_load_dword %0, %1, off sc0 sc1\n\ts_waitcnt vmcnt(0)"
               : "=v"(v) : "v"(p) : "memory");
  return v;
}

// issue one 256-k quarter of h (hi+lo): 4 coherent 16B loads, NO wait.
__device__ __forceinline__ void stage_issue4(const unsigned short* pr0h,
                                             const unsigned short* pr1h,
                                             const unsigned short* pr0l,
                                             const unsigned short* pr1l,
                                             int qoff,   // qtr*256 (shorts)
                                             float4& a, float4& b,
                                             float4& c, float4& d) {
  asm volatile(
      "global_load_dwordx4 %0, %4, off sc0 sc1\n\t"
      "global_load_dwordx4 %1, %5, off sc0 sc1\n\t"
      "global_load_dwordx4 %2, %6, off sc0 sc1\n\t"
      "global_load_dwordx4 %3, %7, off sc0 sc1"
      : "=&v"(a), "=&v"(b), "=&v"(c), "=&v"(d)
      : "v"(pr0h + qoff), "v"(pr1h + qoff), "v"(pr0l + qoff), "v"(pr1l + qoff)
      : "memory");
}

__device__ __forceinline__ void stage_write4(short8* HH, short8* HL,
                                             int b0_, int kg,
                                             const float4& a, const float4& b,
                                             const float4& c, const float4& d) {
  HH[b0_ * 33 + kg]        = __builtin_bit_cast(short8, a);
  HH[(b0_ + 16) * 33 + kg] = __builtin_bit_cast(short8, b);
  HL[b0_ * 33 + kg]        = __builtin_bit_cast(short8, c);
  HL[(b0_ + 16) * 33 + kg] = __builtin_bit_cast(short8, d);
}

// barrier that does NOT drain vmcnt: LDS-drain + raw s_barrier.
__device__ __forceinline__ void lds_barrier() {
  asm volatile("s_waitcnt lgkmcnt(0)" ::: "memory");
  __builtin_amdgcn_sched_barrier(0);
  __builtin_amdgcn_s_barrier();
  __builtin_amdgcn_sched_barrier(0);
}

// ---------------- two-hop root flag barrier (R13) --------------------------

__device__ __forceinline__ void flag_barrier(unsigned* arrive, unsigned* gen,
                                             int blk, int tid, int t) {
  __syncthreads();                         // drains vmcnt per wave
  const unsigned target = (unsigned)(t + 1);
  if (tid == 0) coh_store_u32(arrive + blk * 16, target);
  if (blk == ROOT) {
    if (tid < 64) {
      const unsigned* q0 = arrive + tid * 16;
      const unsigned* q1 = arrive + (64 + tid) * 16;
      const unsigned* q2 = arrive + (128 + tid) * 16;
      const int i3 = (192 + tid < NBLK) ? (192 + tid) : 0;
      const unsigned* q3 = arrive + i3 * 16;
      int guard = 0;
      for (;;) {
        unsigned a, b, c, d;
        asm volatile(
            "global_load_dword %0, %4, off sc0 sc1\n\t"
            "global_load_dword %1, %5, off sc0 sc1\n\t"
            "global_load_dword %2, %6, off sc0 sc1\n\t"
            "global_load_dword %3, %7, off sc0 sc1\n\t"
            "s_waitcnt vmcnt(0)"
            : "=&v"(a), "=&v"(b), "=&v"(c), "=&v"(d)
            : "v"(q0), "v"(q1), "v"(q2), "v"(q3) : "memory");
        bool ok = (a >= target) && (b >= target) && (c >= target) && (d >= target);
        if (__all(ok)) break;
        if (++guard > (1 << 17)) break;    // anti-hang valve
      }
      if (tid == 0) coh_store_u32(gen, target);
    }
  } else {
    if (tid == 0) {
      int guard = 0;
      while (coh_load_u32(gen) < target) {
        __builtin_amdgcn_s_sleep(1);
        if (++guard > (1 << 17)) break;    // anti-hang valve
      }
    }
  }
  __syncthreads();
}

// -------------------------- prep kernels -----------------------------------

__global__ void pack_w(const float* __restrict__ in, unsigned short* __restrict__ hi,
                       unsigned short* __restrict__ lo, int ncols) {
  int id = blockIdx.x * 256 + threadIdx.x;
  int slab = id / ncols, row = id % ncols;   // slab < 128
  int k0 = (slab >> 2) * 32 + (slab & 3) * 8;
  long ob = ((long)slab * ncols + row) * 8;
  #pragma unroll
  for (int e = 0; e < 8; ++e) {
    float w = in[(long)(k0 + e) * ncols + row];
    unsigned h_, l_;
    bf16split(w, h_, l_);
    hi[ob + e] = (unsigned short)h_;
    lo[ob + e] = (unsigned short)l_;
  }
}

__global__ void zero_state(unsigned* __restrict__ p, int n) {
  int i = blockIdx.x * 256 + threadIdx.x;
  if (i < n) p[i] = 0u;
}

// -------------------------- main persistent kernel -------------------------

extern "C" __global__ void __launch_bounds__(512, 1)
lstm_persist(const int* __restrict__ x,
             const float* __restrict__ Wx0,
             const float* __restrict__ b0v,
             const float* __restrict__ b1v,
             const float* __restrict__ byv,
             unsigned short* __restrict__ wss,
             float* __restrict__ out) {
  const short8* wp0h  = (const short8*)(wss + WP0H);
  const short8* wp0l  = (const short8*)(wss + WP0L);
  const short8* wp1xh = (const short8*)(wss + WP1XH);
  const short8* wp1xl = (const short8*)(wss + WP1XL);
  const short8* wp1hh = (const short8*)(wss + WP1HH);
  const short8* wp1hl = (const short8*)(wss + WP1HL);
  const short8* wyh   = (const short8*)(wss + WYH);
  const short8* wyl   = (const short8*)(wss + WYL);
  unsigned short* h0h = wss + HOFF;            // [2][32][1024]
  unsigned short* h0l = h0h + 65536;
  unsigned short* h1h = h0h + 131072;
  unsigned short* h1l = h0h + 196608;
  unsigned* arrive = (unsigned*)(h0h + 262144);  // stride-16 flags
  unsigned* gen = arrive + 4096;

  const int tid = threadIdx.x, blk = blockIdx.x;
  const int lane = tid & 63, m = lane & 15, quad = lane >> 4, w = tid >> 6;
  const int b0_ = tid >> 5, kg = tid & 31;     // staging row / chunk
  const int kg8 = kg * 8;

  __shared__ short8 HSH[2][32 * 33];   // 2 x 16.5 KB  h hi quarter (dbuf)
  __shared__ short8 HSL[2][32 * 33];   // 2 x 16.5 KB  h lo quarter (dbuf)
  __shared__ float gx[4096];           // 16 KB partial-sum exchange

  if (blk < NA) {
    // ================= A: layer0 cell, s = t ===========================
    const int g = w >> 1, kh = w & 1, j0A = blk * 16;
    const int ue = tid >> 5, be = tid & 31, j2e = j0A + ue;
    const float bA0 = b0v[j2e],          bA1 = b0v[kH + j2e];
    const float bA2 = b0v[2 * kH + j2e], bA3 = b0v[3 * kH + j2e];
    // persistent weight slice: 16 kk (parity kh) x hi/lo = 128 VGPR
    const short8* ah_ = wp0h + quad * 4096 + (g * 1024 + j0A + m);
    const short8* al_ = wp0l + quad * 4096 + (g * 1024 + j0A + m);
    short8 wah[16], wal[16];
    #pragma unroll
    for (int i = 0; i < 16; ++i) {
      WLOAD(wah[i], &ah_[(2 * i + kh) * 16384]);
      WLOAD(wal[i], &al_[(2 * i + kh) * 16384]);
    }
    VM_WAIT(0);
    float c0r = 0.f;

    #pragma unroll 1
    for (int t = 0; t < kS + 2; ++t) {
      const int s = t;
      if (s < kS) {
        const int rpar = (s + 1) & 1;
        const unsigned short* gH = h0h + rpar * 32768;
        const unsigned short* gL = h0l + rpar * 32768;
        const unsigned short* pH0 = gH + b0_ * 1024 + kg8;
        const unsigned short* pH1 = pH0 + 16 * 1024;
        const unsigned short* pL0 = gL + b0_ * 1024 + kg8;
        const unsigned short* pL1 = pL0 + 16 * 1024;
        // xs first (compiler load + its own drain), then asm gather, stages
        const int xs = x[be * kS + s];
        const float* wxp = Wx0 + (long)xs * G4H + j2e;
        float wxi, wxf, wxg, wxo;
        asm volatile(
            "global_load_dword %0, %4, off\n\t"
            "global_load_dword %1, %5, off\n\t"
            "global_load_dword %2, %6, off\n\t"
            "global_load_dword %3, %7, off"
            : "=&v"(wxi), "=&v"(wxf), "=&v"(wxg), "=&v"(wxo)
            : "v"(wxp), "v"(wxp + kH), "v"(wxp + 2 * kH), "v"(wxp + 3 * kH)
            : "memory");
        // all 4 quarters upfront: queue = [wx(4), q0..q3(16)]
        float4 st[4][4];
        stage_issue4(pH0, pH1, pL0, pL1, 0,   st[0][0], st[0][1], st[0][2], st[0][3]);
        stage_issue4(pH0, pH1, pL0, pL1, 256, st[1][0], st[1][1], st[1][2], st[1][3]);
        stage_issue4(pH0, pH1, pL0, pL1, 512, st[2][0], st[2][1], st[2][2], st[2][3]);
        stage_issue4(pH0, pH1, pL0, pL1, 768, st[3][0], st[3][1], st[3][2], st[3][3]);
        f32x4 acc0 = {0.f, 0.f, 0.f, 0.f}, acc1 = {0.f, 0.f, 0.f, 0.f};
        #pragma unroll
        for (int ph = 0; ph < 4; ++ph) {
          if (ph == 0)      { VM_WAIT(12); }   // retires wx + q0
          else if (ph == 1) { VM_WAIT(8);  }
          else if (ph == 2) { VM_WAIT(4);  }
          else              { VM_WAIT(0);  }
          stage_write4(&HSH[ph & 1][0], &HSL[ph & 1][0], b0_, kg,
                       st[ph][0], st[ph][1], st[ph][2], st[ph][3]);
          lds_barrier();
          #pragma unroll
          for (int i2 = 0; i2 < 4; ++i2) {
            const int kl = 2 * i2 + kh;          // runtime kh, fine
            const int widx = ph * 4 + i2;        // compile-time
            short8 bh0 = HSH[ph & 1][m * 33 + kl * 4 + quad];
            short8 bl0 = HSL[ph & 1][m * 33 + kl * 4 + quad];
            short8 bh1 = HSH[ph & 1][(16 + m) * 33 + kl * 4 + quad];
            short8 bl1 = HSL[ph & 1][(16 + m) * 33 + kl * 4 + quad];
            acc0 = MFMA(wah[widx], bh0, acc0);
            acc0 = MFMA(wah[widx], bl0, acc0);
            acc0 = MFMA(wal[widx], bh0, acc0);
            acc1 = MFMA(wah[widx], bh1, acc1);
            acc1 = MFMA(wah[widx], bl1, acc1);
            acc1 = MFMA(wal[widx], bh1, acc1);
          }
        }
        #pragma unroll
        for (int r = 0; r < 4; ++r) {
          gx[(kh * 64 + g * 16 + quad * 4 + r) * 32 + m]      = acc0[r];
          gx[(kh * 64 + g * 16 + quad * 4 + r) * 32 + 16 + m] = acc1[r];
        }
        lds_barrier();
        {
          float gi = gx[(0 + ue) * 32 + be]  + gx[(64 + 0 + ue) * 32 + be]  + wxi + bA0;
          float gf = gx[(16 + ue) * 32 + be] + gx[(64 + 16 + ue) * 32 + be] + wxf + bA1;
          float gg = gx[(32 + ue) * 32 + be] + gx[(64 + 32 + ue) * 32 + be] + wxg + bA2;
          float go = gx[(48 + ue) * 32 + be] + gx[(64 + 48 + ue) * 32 + be] + wxo + bA3;
          float cc = sigmoidf_(gf) * c0r + sigmoidf_(gi) * tanhf(gg);
          float hh = sigmoidf_(go) * tanhf(cc);
          c0r = cc;
          unsigned h_, l_;
          bf16split(hh, h_, l_);
          const int wpar = s & 1;
          coh_store_u16(h0h + wpar * 32768 + be * 1024 + j2e, h_);
          coh_store_u16(h0l + wpar * 32768 + be * 1024 + j2e, l_);
        }
      }
      if (t < kS + 1) flag_barrier(arrive, gen, blk, tid, t);
    }
  } else if (blk < C0) {
    // ================= B: layer1 cell, s = t-1 =========================
    const int hf = w >> 2, mt = (w >> 1) & 1, kq = w & 1;
    const int rowB = mt * 16 + m;
    const int growB = (rowB >> 3) * 1024 + (blk - B0) * 8 + (rowB & 7);
    const int ub = tid >> 5;
    const int j2b = (blk - B0) * 8 + (ub & 7);
    const float bB0 = b1v[j2b],          bB1 = b1v[kH + j2b];
    const float bB2 = b1v[2 * kH + j2b], bB3 = b1v[3 * kH + j2b];
    // persistent slice: matrix hf, 16 kk (parity kq) x hi/lo = 128 VGPR
    const short8* bh_ = (hf ? wp1hh : wp1xh) + quad * 4096 + growB;
    const short8* bl_ = (hf ? wp1hl : wp1xl) + quad * 4096 + growB;
    short8 wbh[16], wbl[16];
    #pragma unroll
    for (int i = 0; i < 16; ++i) {
      WLOAD(wbh[i], &bh_[(2 * i + kq) * 16384]);
      WLOAD(wbl[i], &bl_[(2 * i + kq) * 16384]);
    }
    VM_WAIT(0);
    float c1r = 0.f;

    #pragma unroll 1
    for (int t = 0; t < kS + 2; ++t) {
      const int s = t - 1;
      if (s >= 0 && s < kS) {
        const unsigned short* g0h = h0h + (s & 1) * 32768;
        const unsigned short* g0l = h0l + (s & 1) * 32768;
        const unsigned short* g1h = h1h + ((s + 1) & 1) * 32768;
        const unsigned short* g1l = h1l + ((s + 1) & 1) * 32768;
        const unsigned short* pA0h = g0h + b0_ * 1024 + kg8;
        const unsigned short* pA1h = pA0h + 16 * 1024;
        const unsigned short* pA0l = g0l + b0_ * 1024 + kg8;
        const unsigned short* pA1l = pA0l + 16 * 1024;
        const unsigned short* pB0h = g1h + b0_ * 1024 + kg8;
        const unsigned short* pB1h = pB0h + 16 * 1024;
        const unsigned short* pB0l = g1l + b0_ * 1024 + kg8;
        const unsigned short* pB1l = pB0l + 16 * 1024;
        // q0..q3 (h0) upfront; q4..q7 (h1) reissued per phase after barrier
        float4 st[4][4];
        stage_issue4(pA0h, pA1h, pA0l, pA1l, 0,   st[0][0], st[0][1], st[0][2], st[0][3]);
        stage_issue4(pA0h, pA1h, pA0l, pA1l, 256, st[1][0], st[1][1], st[1][2], st[1][3]);
        stage_issue4(pA0h, pA1h, pA0l, pA1l, 512, st[2][0], st[2][1], st[2][2], st[2][3]);
        stage_issue4(pA0h, pA1h, pA0l, pA1l, 768, st[3][0], st[3][1], st[3][2], st[3][3]);
        f32x4 acc0 = {0.f, 0.f, 0.f, 0.f}, acc1 = {0.f, 0.f, 0.f, 0.f};
        #pragma unroll
        for (int ph = 0; ph < 8; ++ph) {
          const int half = ph >> 2, qtr = ph & 3;
          if (ph < 5)       { VM_WAIT(12); }
          else if (ph == 5) { VM_WAIT(8);  }
          else if (ph == 6) { VM_WAIT(4);  }
          else              { VM_WAIT(0);  }
          stage_write4(&HSH[ph & 1][0], &HSL[ph & 1][0], b0_, kg,
                       st[ph & 3][0], st[ph & 3][1], st[ph & 3][2], st[ph & 3][3]);
          lds_barrier();           // lgkmcnt(0) first -> slot regs reusable
          if (ph < 4)              // issue q(ph+4) into the slot just drained
            stage_issue4(pB0h, pB1h, pB0l, pB1l, ph * 256,
                         st[ph & 3][0], st[ph & 3][1], st[ph & 3][2], st[ph & 3][3]);
          if (hf == half) {
            #pragma unroll
            for (int i2 = 0; i2 < 4; ++i2) {
              const int kl = 2 * i2 + kq;
              const int widx = qtr * 4 + i2;
              short8 bh0 = HSH[ph & 1][m * 33 + kl * 4 + quad];
              short8 bl0 = HSL[ph & 1][m * 33 + kl * 4 + quad];
              short8 bh1 = HSH[ph & 1][(16 + m) * 33 + kl * 4 + quad];
              short8 bl1 = HSL[ph & 1][(16 + m) * 33 + kl * 4 + quad];
              acc0 = MFMA(wbh[widx], bh0, acc0);
              acc0 = MFMA(wbh[widx], bl0, acc0);
              acc0 = MFMA(wbl[widx], bh0, acc0);
              acc1 = MFMA(wbh[widx], bh1, acc1);
              acc1 = MFMA(wbh[widx], bl1, acc1);
              acc1 = MFMA(wbl[widx], bh1, acc1);
            }
          }
        }
        #pragma unroll
        for (int r = 0; r < 4; ++r) {
          const int rg = hf * 2 + kq;
          gx[(rg * 32 + mt * 16 + quad * 4 + r) * 32 + m]      = acc0[r];
          gx[(rg * 32 + mt * 16 + quad * 4 + r) * 32 + 16 + m] = acc1[r];
        }
        lds_barrier();
        if (tid < 256) {
          const int u = tid >> 5, b = tid & 31;
          float gt[4];
          #pragma unroll
          for (int g2 = 0; g2 < 4; ++g2) {
            const int row = g2 * 8 + u;
            gt[g2] = gx[(row) * 32 + b] + gx[(32 + row) * 32 + b] +
                     gx[(64 + row) * 32 + b] + gx[(96 + row) * 32 + b];
          }
          float gt0 = gt[0] + bB0, gt1 = gt[1] + bB1;
          float gt2 = gt[2] + bB2, gt3 = gt[3] + bB3;
          float cc = sigmoidf_(gt1) * c1r + sigmoidf_(gt0) * tanhf(gt2);
          float hh = sigmoidf_(gt3) * tanhf(cc);
          c1r = cc;
          unsigned h_, l_;
          bf16split(hh, h_, l_);
          const int wpar = s & 1;
          const int j2 = (blk - B0) * 8 + u;
          coh_store_u16(h1h + wpar * 32768 + b * 1024 + j2, h_);
          coh_store_u16(h1l + wpar * 32768 + b * 1024 + j2, l_);
        }
      }
      if (t < kS + 1) flag_barrier(arrive, gen, blk, tid, t);
    }
  } else {
    // ================= C: vocab projection, s = t-2 ====================
    const int growC = (blk - C0) * 16 + m;
    const float byr = byv[(blk - C0) * 16 + (tid & 15)];
    // persistent slice: 4 kk (kl == w) x hi/lo = 32 VGPR
    const short8* ch_ = wyh + quad * 256 + growC;
    const short8* cl_ = wyl + quad * 256 + growC;
    short8 wch[4], wcl[4];
    #pragma unroll
    for (int i = 0; i < 4; ++i) {
      WLOAD(wch[i], &ch_[(i * 8 + w) * 1024]);
      WLOAD(wcl[i], &cl_[(i * 8 + w) * 1024]);
    }
    VM_WAIT(0);

    #pragma unroll 1
    for (int t = 0; t < kS + 2; ++t) {
      const int s = t - 2;
      if (s >= 0 && s < kS) {
        const int rpar = s & 1;
        const unsigned short* gH = h1h + rpar * 32768;
        const unsigned short* gL = h1l + rpar * 32768;
        const unsigned short* pH0 = gH + b0_ * 1024 + kg8;
        const unsigned short* pH1 = pH0 + 16 * 1024;
        const unsigned short* pL0 = gL + b0_ * 1024 + kg8;
        const unsigned short* pL1 = pL0 + 16 * 1024;
        float4 st[4][4];
        stage_issue4(pH0, pH1, pL0, pL1, 0,   st[0][0], st[0][1], st[0][2], st[0][3]);
        stage_issue4(pH0, pH1, pL0, pL1, 256, st[1][0], st[1][1], st[1][2], st[1][3]);
        stage_issue4(pH0, pH1, pL0, pL1, 512, st[2][0], st[2][1], st[2][2], st[2][3]);
        stage_issue4(pH0, pH1, pL0, pL1, 768, st[3][0], st[3][1], st[3][2], st[3][3]);
        f32x4 acc0 = {0.f, 0.f, 0.f, 0.f}, acc1 = {0.f, 0.f, 0.f, 0.f};
        #pragma unroll
        for (int ph = 0; ph < 4; ++ph) {
          if (ph == 0)      { VM_WAIT(12); }
          else if (ph == 1) { VM_WAIT(8);  }
          else if (ph == 2) { VM_WAIT(4);  }
          else              { VM_WAIT(0);  }
          stage_write4(&HSH[ph & 1][0], &HSL[ph & 1][0], b0_, kg,
                       st[ph][0], st[ph][1], st[ph][2], st[ph][3]);
          lds_barrier();
          {
            const int kl = w;                  // wave-uniform
            short8 bh0 = HSH[ph & 1][m * 33 + kl * 4 + quad];
            short8 bl0 = HSL[ph & 1][m * 33 + kl * 4 + quad];
            short8 bh1 = HSH[ph & 1][(16 + m) * 33 + kl * 4 + quad];
            short8 bl1 = HSL[ph & 1][(16 + m) * 33 + kl * 4 + quad];
            acc0 = MFMA(wch[ph], bh0, acc0);
            acc0 = MFMA(wch[ph], bl0, acc0);
            acc0 = MFMA(wcl[ph], bh0, acc0);
            acc1 = MFMA(wch[ph], bh1, acc1);
            acc1 = MFMA(wch[ph], bl1, acc1);
            acc1 = MFMA(wcl[ph], bh1, acc1);
          }
        }
        #pragma unroll
        for (int r = 0; r < 4; ++r) {
          gx[(w * 16 + quad * 4 + r) * 32 + m]      = acc0[r];
          gx[(w * 16 + quad * 4 + r) * 32 + 16 + m] = acc1[r];
        }
        lds_barrier();
        {
          const int b = tid >> 4, vl = tid & 15;
          const int vg = (blk - C0) * 16 + vl;
          float sum = byr;
          #pragma unroll
          for (int rg = 0; rg < 8; ++rg) sum += gx[(rg * 16 + vl) * 32 + b];
          out[(s * kB + b) * kV + vg] = sum;
        }
      }
      if (t < kS + 1) flag_barrier(arrive, gen, blk, tid, t);
    }
  }
}

// -------------------------- host launcher ----------------------------------

extern "C" void kernel_launch(void* const* d_in, const int* in_sizes, int n_in,
                              void* d_out, int out_size, void* d_ws, size_t ws_size,
                              hipStream_t stream) {
  const int*   x   = (const int*)d_in[0];
  const float* Wx0 = (const float*)d_in[1];
  const float* Wh0 = (const float*)d_in[2];
  const float* b0v = (const float*)d_in[3];
  const float* Wx1 = (const float*)d_in[4];
  const float* Wh1 = (const float*)d_in[5];
  const float* b1v = (const float*)d_in[6];
  const float* Why = (const float*)d_in[7];
  const float* byv = (const float*)d_in[8];
  unsigned short* wss = (unsigned short*)d_ws;
  float* outp = (float*)d_out;

  hipLaunchKernelGGL(pack_w, dim3(2048), dim3(256), 0, stream,
                     Wh0, wss + WP0H, wss + WP0L, G4H);
  hipLaunchKernelGGL(pack_w, dim3(2048), dim3(256), 0, stream,
                     Wx1, wss + WP1XH, wss + WP1XL, G4H);
  hipLaunchKernelGGL(pack_w, dim3(2048), dim3(256), 0, stream,
                     Wh1, wss + WP1HH, wss + WP1HL, G4H);
  hipLaunchKernelGGL(pack_w, dim3(128), dim3(256), 0, stream,
                     Why, wss + WYH, wss + WYL, kV);
  // zero h arrays (262144 shorts = 131072 u32) + flags/gen (4097 u32)
  hipLaunchKernelGGL(zero_state, dim3(529), dim3(256), 0, stream,
                     (unsigned*)(wss + HOFF), 131072 + 4100);

  hipLaunchKernelGGL(lstm_persist, dim3(NBLK), dim3(NT), 0, stream,
                     x, Wx0, b0v, b1v, byv, wss, outp);
}